// Round 1
// baseline (276.042 us; speedup 1.0000x reference)
//
#include <hip/hip_runtime.h>
#include <cmath>

// Problem constants
#define BATCH 8
#define HF 512
#define WF 512
#define HS 256
#define WS 256
#define PLANE_S (HS * WS)   // 65536
#define PLANE_F (HF * WF)   // 262144
#define MB (1048576)

// Workspace layout (bytes)
#define OFF_PF    (0)                 // pooled fixed:  8 * 65536 f  (2 MB)
#define OFF_PM    (2 * MB)            // pooled moved:  2 MB
#define OFF_PFLOW (4 * MB)            // pooled flow:   16 planes (4 MB)
#define OFF_VF    (8 * MB)            // variance F:    2 MB
#define OFF_VM    (10 * MB)           // variance M:    2 MB
#define OFF_DIFF  (12 * MB)           // mind diff:     8*8*65536 f (16 MB); tF/tM overlap here
#define OFF_TF    (OFF_DIFF)          // temp (img-mean)^2 F (2 MB, dead before diff written)
#define OFF_TM    (OFF_DIFF + 2 * MB) // temp M (2 MB)
#define OFF_HIST  (28 * MB)           // 8 * 256 u32
#define OFF_NMI   (28 * MB + 8192)    // 8 f32
#define OFF_ACC   (28 * MB + 8192 + 32) // 3 doubles: mind_sum, grad_sum, lap_sum

__device__ __forceinline__ int clampi(int v, int lo, int hi) {
    return v < lo ? lo : (v > hi ? hi : v);
}

__global__ void init_kernel(unsigned* hist, float* nmi, double* acc) {
    int t = threadIdx.x;
    for (int i = t; i < BATCH * 256; i += 256) hist[i] = 0u;
    if (t < BATCH) nmi[t] = 0.f;
    if (t < 3) acc[t] = 0.0;
}

// avg_pool2: 512x512 plane -> 256x256 plane (mean of 2x2)
__global__ void pool_kernel(const float* __restrict__ src, float* __restrict__ dst, int nplanes) {
    int idx = blockIdx.x * blockDim.x + threadIdx.x;
    if (idx >= nplanes * PLANE_S) return;
    int p = idx >> 16;
    int r = idx & (PLANE_S - 1);
    int y = r >> 8, x = r & 255;
    const float* s = src + (size_t)p * PLANE_F + (size_t)(y * 2) * WF + (x * 2);
    dst[idx] = (s[0] + s[1] + s[WF] + s[WF + 1]) * 0.25f;
}

// t = (img[y,x] - boxmean centered at (y-1,x-1))^2   [the reference's pad/slice quirk]
__global__ void patchvar1_kernel(const float* __restrict__ img, float* __restrict__ t) {
    int idx = blockIdx.x * blockDim.x + threadIdx.x;
    if (idx >= BATCH * PLANE_S) return;
    int b = idx >> 16;
    int r = idx & (PLANE_S - 1);
    int y = r >> 8, x = r & 255;
    const float* p = img + (size_t)b * PLANE_S;
    float s = 0.f;
    #pragma unroll
    for (int dy = -2; dy <= 0; dy++) {
        int yy = clampi(y + dy, 0, HS - 1);
        #pragma unroll
        for (int dx = -2; dx <= 0; dx++) {
            int xx = clampi(x + dx, 0, WS - 1);
            s += p[yy * WS + xx];
        }
    }
    float mean = s / 9.0f;
    float d = p[r] - mean;
    t[idx] = d * d;
}

// var = max(box3x3(t)/9, 1e-4)
__global__ void patchvar2_kernel(const float* __restrict__ t, float* __restrict__ var) {
    int idx = blockIdx.x * blockDim.x + threadIdx.x;
    if (idx >= BATCH * PLANE_S) return;
    int b = idx >> 16;
    int r = idx & (PLANE_S - 1);
    int y = r >> 8, x = r & 255;
    const float* p = t + (size_t)b * PLANE_S;
    float s = 0.f;
    #pragma unroll
    for (int dy = -1; dy <= 1; dy++) {
        int yy = clampi(y + dy, 0, HS - 1);
        #pragma unroll
        for (int dx = -1; dx <= 1; dx++) {
            int xx = clampi(x + dx, 0, WS - 1);
            s += p[yy * WS + xx];
        }
    }
    var[idx] = fmaxf(s / 9.0f, 1e-4f);
}

// MIND descriptors for both images, store diff = mF - mM, channel-major planes
__global__ void mind_kernel(const float* __restrict__ pf, const float* __restrict__ pm,
                            const float* __restrict__ vF, const float* __restrict__ vM,
                            float* __restrict__ diff) {
    int idx = blockIdx.x * blockDim.x + threadIdx.x;
    if (idx >= BATCH * PLANE_S) return;
    int b = idx >> 16;
    int r = idx & (PLANE_S - 1);
    int y = r >> 8, x = r & 255;
    const float* f = pf + (size_t)b * PLANE_S;
    const float* m = pm + (size_t)b * PLANE_S;
    float cF = f[r], cM = m[r];
    float dF2 = 2.f * vF[idx] + 1e-6f;
    float dM2 = 2.f * vM[idx] + 1e-6f;
    float eF[8], eM[8];
    float sF = 0.f, sM = 0.f;
    int ch = 0;
    #pragma unroll
    for (int i = -1; i <= 1; i++) {
        #pragma unroll
        for (int j = -1; j <= 1; j++) {
            if (i == 0 && j == 0) continue;
            int yy = clampi(y + j * 2, 0, HS - 1);
            int xx = clampi(x + i * 2, 0, WS - 1);
            int o = yy * WS + xx;
            float aF = cF - f[o];
            float aM = cM - m[o];
            float qF = fminf(aF * aF / dF2, 50.f);
            float qM = fminf(aM * aM / dM2, 50.f);
            float vFe = expf(-qF), vMe = expf(-qM);
            eF[ch] = vFe; eM[ch] = vMe;
            sF += vFe; sM += vMe;
            ch++;
        }
    }
    float wF = 1.f / (sF + 1e-8f);
    float wM = 1.f / (sM + 1e-8f);
    float* dbase = diff + (size_t)b * 8 * PLANE_S + r;
    #pragma unroll
    for (int c = 0; c < 8; c++) dbase[(size_t)c * PLANE_S] = eF[c] * wF - eM[c] * wM;
}

// bilinear align-corners upsample 256->512 of diff, accumulate sum(|.|)
__global__ void mindsum_kernel(const float* __restrict__ diff, double* __restrict__ acc) {
    const float FS = (float)(255.0 / 511.0);
    const long long N = 64LL * PLANE_F;  // 8 batches * 8 ch * 512*512
    long long stride = (long long)gridDim.x * blockDim.x;
    double local = 0.0;
    for (long long e = blockIdx.x * (long long)blockDim.x + threadIdx.x; e < N; e += stride) {
        int pc = (int)(e >> 18);          // plane (b*8+ch)
        int r = (int)(e & (PLANE_F - 1));
        int Y = r >> 9, X = r & 511;
        float py = (float)Y * FS;
        int y0 = (int)py; if (y0 > HS - 2) y0 = HS - 2;
        float fy = py - (float)y0;
        float px = (float)X * FS;
        int x0 = (int)px; if (x0 > WS - 2) x0 = WS - 2;
        float fx = px - (float)x0;
        const float* pl = diff + (size_t)pc * PLANE_S;
        const float* r0 = pl + y0 * WS;
        const float* r1 = r0 + WS;
        float a = r0[x0] * (1.f - fy) + r1[x0] * fy;
        float c = r0[x0 + 1] * (1.f - fy) + r1[x0 + 1] * fy;
        float v = a * (1.f - fx) + c * fx;
        local += (double)fabsf(v);
    }
    __shared__ double red[256];
    int t = threadIdx.x;
    red[t] = local;
    __syncthreads();
    for (int s = 128; s > 0; s >>= 1) { if (t < s) red[t] += red[t + s]; __syncthreads(); }
    if (t == 0) atomicAdd(acc, red[0]);
}

__device__ __forceinline__ int bin_of(float x) {
    float v = (x + 1.0f) * 0.5f;
    v = fminf(fmaxf(v, 0.001f), 0.999f);
    float t = v * 16.0f;            // exact (power-of-2 scale)
    float ft = floorf(t);
    int c = (int)ft + ((t > ft) ? 1 : 0);   // searchsorted-left count of grid < v
    int b = c - 1;
    return b < 0 ? 0 : (b > 15 ? 15 : b);
}

// per-batch joint 16x16 histogram of strided-sampled fixed/moved
__global__ void hist_kernel(const float* __restrict__ fixed, const float* __restrict__ moved,
                            unsigned* __restrict__ hist) {
    int b = blockIdx.y;
    __shared__ unsigned lh[256];
    lh[threadIdx.x] = 0u;
    __syncthreads();
    int stride = gridDim.x * blockDim.x;             // 4096
    int per = PLANE_S / stride;                      // 16
    int start = blockIdx.x * blockDim.x + threadIdx.x;
    const float* fb = fixed + (size_t)b * PLANE_F;
    const float* mb = moved + (size_t)b * PLANE_F;
    for (int k = 0; k < per; k++) {
        int s = start + k * stride;
        int r = s >> 8, c = s & 255;
        size_t o = (size_t)r * 1024 + (size_t)c * 2;  // (2r)*512 + 2c
        int xb = bin_of(fb[o]);
        int yb = bin_of(mb[o]);
        atomicAdd(&lh[xb * 16 + yb], 1u);
    }
    __syncthreads();
    atomicAdd(&hist[b * 256 + threadIdx.x], lh[threadIdx.x]);
}

// per-batch NMI from joint histogram
__global__ void nmi_kernel(const unsigned* __restrict__ hist, float* __restrict__ nmi_out) {
    int b = blockIdx.x;
    int t = threadIdx.x;  // 256
    __shared__ float p[256];
    __shared__ float xh[16], yh[16];
    __shared__ float red[256];
    float pv = (float)hist[b * 256 + t] / 65536.0f;  // sum+1e-10 == 65536 in fp32
    p[t] = pv;
    __syncthreads();
    if (t < 16) {
        float s = 0.f;
        for (int j = 0; j < 16; j++) s += p[t * 16 + j];
        xh[t] = s;
    } else if (t < 32) {
        int j = t - 16;
        float s = 0.f;
        for (int i = 0; i < 16; i++) s += p[i * 16 + j];
        yh[j] = s;
    }
    __syncthreads();
    const float eps = 1e-5f;
    int i = t >> 4, j = t & 15;
    float h = pv + eps;
    float mi_term = h * (logf(h) - logf((xh[i] + eps) * (yh[j] + eps)));
    red[t] = mi_term;
    __syncthreads();
    for (int s = 128; s > 0; s >>= 1) { if (t < s) red[t] += red[t + s]; __syncthreads(); }
    float mi = red[0];
    __syncthreads();
    float e_term = 0.f;
    if (t < 16) { float xe = xh[t] + eps; e_term = -xe * logf(xe); }
    else if (t < 32) { float ye = yh[t - 16] + eps; e_term = -ye * logf(ye); }
    red[t] = e_term;
    __syncthreads();
    for (int s = 128; s > 0; s >>= 1) { if (t < s) red[t] += red[t + s]; __syncthreads(); }
    if (t == 0) {
        float se = red[0];  // hx + hy
        float nmi = (se < 1e-10f) ? 0.f : 2.f * mi / se;
        nmi_out[b] = fminf(fmaxf(nmi, -1.f), 1.f);
    }
}

// Sobel grad + Laplacian magnitudes on pooled flow, clipped means
__global__ void reg_kernel(const float* __restrict__ pflow, double* __restrict__ acc_grad,
                           double* __restrict__ acc_lap) {
    __shared__ double red[256];
    int idx = blockIdx.x * blockDim.x + threadIdx.x;
    double g = 0.0, l = 0.0;
    if (idx < BATCH * PLANE_S) {
        int b = idx >> 16;
        int r = idx & (PLANE_S - 1);
        int y = r >> 8, x = r & 255;
        const float* u = pflow + (size_t)b * 2 * PLANE_S;
        const float* v = u + PLANE_S;
        float a[3][3], c[3][3];
        #pragma unroll
        for (int dy = 0; dy < 3; dy++) {
            int yy = clampi(y + dy - 1, 0, HS - 1);
            #pragma unroll
            for (int dx = 0; dx < 3; dx++) {
                int xx = clampi(x + dx - 1, 0, WS - 1);
                a[dy][dx] = u[yy * WS + xx];
                c[dy][dx] = v[yy * WS + xx];
            }
        }
        float gxu = (a[0][2] - a[0][0]) + 2.f * (a[1][2] - a[1][0]) + (a[2][2] - a[2][0]);
        float gyu = (a[2][0] - a[0][0]) + 2.f * (a[2][1] - a[0][1]) + (a[2][2] - a[0][2]);
        float gxv = (c[0][2] - c[0][0]) + 2.f * (c[1][2] - c[1][0]) + (c[2][2] - c[2][0]);
        float gyv = (c[2][0] - c[0][0]) + 2.f * (c[2][1] - c[0][1]) + (c[2][2] - c[0][2]);
        float lpu = a[0][1] + a[1][0] - 4.f * a[1][1] + a[1][2] + a[2][1];
        float lpv = c[0][1] + c[1][0] - 4.f * c[1][1] + c[1][2] + c[2][1];
        float grad = gxu * gxu + gyu * gyu + gxv * gxv + gyv * gyv;
        float lap = lpu * lpu + lpv * lpv;
        g = (double)fminf(grad, 100.f);
        l = (double)fminf(lap, 100.f);
    }
    int t = threadIdx.x;
    red[t] = g;
    __syncthreads();
    for (int s = 128; s > 0; s >>= 1) { if (t < s) red[t] += red[t + s]; __syncthreads(); }
    if (t == 0) atomicAdd(acc_grad, red[0]);
    __syncthreads();
    red[t] = l;
    __syncthreads();
    for (int s = 128; s > 0; s >>= 1) { if (t < s) red[t] += red[t + s]; __syncthreads(); }
    if (t == 0) atomicAdd(acc_lap, red[0]);
}

__global__ void final_kernel(const float* __restrict__ nmi, const double* __restrict__ acc,
                             float* __restrict__ out) {
    float s = 0.f;
    for (int b = 0; b < BATCH; b++) s += nmi[b];
    s /= (float)BATCH;
    s = fminf(fmaxf(s, -1.f), 1.f);
    double mi_loss = -(double)s;
    double mind_mean = acc[0] / (64.0 * (double)PLANE_F);
    double reg = acc[1] / (double)(BATCH * PLANE_S) + acc[2] / (double)(BATCH * PLANE_S);
    out[0] = (float)(mi_loss + 5.0 * mind_mean + 0.1 * reg);
}

extern "C" void kernel_launch(void* const* d_in, const int* in_sizes, int n_in,
                              void* d_out, int out_size, void* d_ws, size_t ws_size,
                              hipStream_t stream) {
    const float* fixed = (const float*)d_in[0];
    const float* moved = (const float*)d_in[1];
    const float* flow  = (const float*)d_in[2];
    float* out = (float*)d_out;
    char* ws = (char*)d_ws;

    float*    pf    = (float*)(ws + OFF_PF);
    float*    pm    = (float*)(ws + OFF_PM);
    float*    pflow = (float*)(ws + OFF_PFLOW);
    float*    vF    = (float*)(ws + OFF_VF);
    float*    vM    = (float*)(ws + OFF_VM);
    float*    diffb = (float*)(ws + OFF_DIFF);
    float*    tF    = (float*)(ws + OFF_TF);
    float*    tM    = (float*)(ws + OFF_TM);
    unsigned* hist  = (unsigned*)(ws + OFF_HIST);
    float*    nmi   = (float*)(ws + OFF_NMI);
    double*   acc   = (double*)(ws + OFF_ACC);

    init_kernel<<<1, 256, 0, stream>>>(hist, nmi, acc);

    // pooling: fixed (8 planes), moved (8), flow (16)
    pool_kernel<<<(BATCH * PLANE_S) / 256, 256, 0, stream>>>(fixed, pf, BATCH);
    pool_kernel<<<(BATCH * PLANE_S) / 256, 256, 0, stream>>>(moved, pm, BATCH);
    pool_kernel<<<(2 * BATCH * PLANE_S) / 256, 256, 0, stream>>>(flow, pflow, 2 * BATCH);

    // MIND variance (2 passes each) — tF/tM live in the diff region, dead before mind writes it
    patchvar1_kernel<<<(BATCH * PLANE_S) / 256, 256, 0, stream>>>(pf, tF);
    patchvar1_kernel<<<(BATCH * PLANE_S) / 256, 256, 0, stream>>>(pm, tM);
    patchvar2_kernel<<<(BATCH * PLANE_S) / 256, 256, 0, stream>>>(tF, vF);
    patchvar2_kernel<<<(BATCH * PLANE_S) / 256, 256, 0, stream>>>(tM, vM);

    mind_kernel<<<(BATCH * PLANE_S) / 256, 256, 0, stream>>>(pf, pm, vF, vM, diffb);
    mindsum_kernel<<<8192, 256, 0, stream>>>(diffb, &acc[0]);

    hist_kernel<<<dim3(16, BATCH), 256, 0, stream>>>(fixed, moved, hist);
    nmi_kernel<<<BATCH, 256, 0, stream>>>(hist, nmi);

    reg_kernel<<<(BATCH * PLANE_S) / 256, 256, 0, stream>>>(pflow, &acc[1], &acc[2]);

    final_kernel<<<1, 1, 0, stream>>>(nmi, acc, out);
}

// Round 2
// 188.995 us; speedup vs baseline: 1.4606x; 1.4606x over previous
//
#include <hip/hip_runtime.h>
#include <cmath>

// Problem constants
#define BATCH 8
#define HF 512
#define WF 512
#define HS 256
#define WS 256
#define PLANE_S (HS * WS)   // 65536
#define PLANE_F (HF * WF)   // 262144
#define MB (1048576)

// Workspace layout (bytes)
#define OFF_PF    (0)                 // pooled fixed:  8 * 65536 f  (2 MB)
#define OFF_PM    (2 * MB)            // pooled moved:  2 MB (contiguous after PF)
#define OFF_PFLOW (4 * MB)            // pooled flow:   16 planes (4 MB)
#define OFF_VF    (8 * MB)            // variance F:    2 MB
#define OFF_VM    (10 * MB)           // variance M:    2 MB (contiguous after VF)
#define OFF_DIFF  (12 * MB)           // mind diff:     8*8*65536 f (16 MB); tF/tM overlap here
#define OFF_TF    (OFF_DIFF)          // temp (img-mean)^2 F+M (4 MB, dead before diff written)
#define OFF_HIST  (28 * MB)           // 8 * 256 u32
#define OFF_NMI   (28 * MB + 8192)    // 8 f32
#define OFF_ACC   (28 * MB + 8192 + 32) // 3 doubles: mind_sum, grad_sum, lap_sum

__device__ __forceinline__ int clampi(int v, int lo, int hi) {
    return v < lo ? lo : (v > hi ? hi : v);
}

__global__ void init_kernel(unsigned* hist, float* nmi, double* acc) {
    int t = threadIdx.x;
    for (int i = t; i < BATCH * 256; i += 256) hist[i] = 0u;
    if (t < BATCH) nmi[t] = 0.f;
    if (t < 3) acc[t] = 0.0;
}

__device__ __forceinline__ int bin_of(float x) {
    float v = (x + 1.0f) * 0.5f;
    v = fminf(fmaxf(v, 0.001f), 0.999f);
    float t = v * 16.0f;            // exact (power-of-2 scale)
    float ft = floorf(t);
    int c = (int)ft + ((t > ft) ? 1 : 0);   // searchsorted-left count of grid < v
    int b = c - 1;
    return b < 0 ? 0 : (b > 15 ? 15 : b);
}

// Fused: avg_pool2 of fixed & moved + joint 16x16 histogram of the ::2,::2 samples
// (the ::2,::2 sample IS the top-left element of each pool window)
__global__ void pool_fm_hist_kernel(const float* __restrict__ fixed, const float* __restrict__ moved,
                                    float* __restrict__ pf, float* __restrict__ pm,
                                    unsigned* __restrict__ hist) {
    int b = blockIdx.y;
    __shared__ unsigned lh[256];
    lh[threadIdx.x] = 0u;
    __syncthreads();
    int idx = blockIdx.x * 256 + threadIdx.x;   // 0..65535 within plane
    int y = idx >> 8, x = idx & 255;
    size_t so = (size_t)b * PLANE_F + (size_t)(y * 2) * WF + (size_t)(x * 2);
    const float* fb = fixed + so;
    const float* mb = moved + so;
    float f00 = fb[0], f01 = fb[1], f10 = fb[WF], f11 = fb[WF + 1];
    float m00 = mb[0], m01 = mb[1], m10 = mb[WF], m11 = mb[WF + 1];
    pf[(size_t)b * PLANE_S + idx] = (f00 + f01 + f10 + f11) * 0.25f;
    pm[(size_t)b * PLANE_S + idx] = (m00 + m01 + m10 + m11) * 0.25f;
    int xb = bin_of(f00), yb = bin_of(m00);
    atomicAdd(&lh[xb * 16 + yb], 1u);
    __syncthreads();
    unsigned v = lh[threadIdx.x];
    if (v) atomicAdd(&hist[b * 256 + threadIdx.x], v);
}

// plain avg_pool2 for flow (16 planes)
__global__ void pool_kernel(const float* __restrict__ src, float* __restrict__ dst, int nplanes) {
    int idx = blockIdx.x * blockDim.x + threadIdx.x;
    if (idx >= nplanes * PLANE_S) return;
    int p = idx >> 16;
    int r = idx & (PLANE_S - 1);
    int y = r >> 8, x = r & 255;
    const float* s = src + (size_t)p * PLANE_F + (size_t)(y * 2) * WF + (x * 2);
    dst[idx] = (s[0] + s[1] + s[WF] + s[WF + 1]) * 0.25f;
}

// t = (img[y,x] - boxmean centered at (y-1,x-1))^2   [reference pad/slice quirk]
// processes nplanes contiguous planes (pf and pm are contiguous)
__global__ void patchvar1_kernel(const float* __restrict__ img, float* __restrict__ t, int nplanes) {
    int idx = blockIdx.x * blockDim.x + threadIdx.x;
    if (idx >= nplanes * PLANE_S) return;
    int p = idx >> 16;
    int r = idx & (PLANE_S - 1);
    int y = r >> 8, x = r & 255;
    const float* pp = img + (size_t)p * PLANE_S;
    float s = 0.f;
    #pragma unroll
    for (int dy = -2; dy <= 0; dy++) {
        int yy = clampi(y + dy, 0, HS - 1);
        #pragma unroll
        for (int dx = -2; dx <= 0; dx++) {
            int xx = clampi(x + dx, 0, WS - 1);
            s += pp[yy * WS + xx];
        }
    }
    float mean = s / 9.0f;
    float d = pp[r] - mean;
    t[idx] = d * d;
}

// var = max(box3x3(t)/9, 1e-4)
__global__ void patchvar2_kernel(const float* __restrict__ t, float* __restrict__ var, int nplanes) {
    int idx = blockIdx.x * blockDim.x + threadIdx.x;
    if (idx >= nplanes * PLANE_S) return;
    int p = idx >> 16;
    int r = idx & (PLANE_S - 1);
    int y = r >> 8, x = r & 255;
    const float* pp = t + (size_t)p * PLANE_S;
    float s = 0.f;
    #pragma unroll
    for (int dy = -1; dy <= 1; dy++) {
        int yy = clampi(y + dy, 0, HS - 1);
        #pragma unroll
        for (int dx = -1; dx <= 1; dx++) {
            int xx = clampi(x + dx, 0, WS - 1);
            s += pp[yy * WS + xx];
        }
    }
    var[idx] = fmaxf(s / 9.0f, 1e-4f);
}

// MIND descriptors for both images, store diff = mF - mM, channel-major planes
__global__ void mind_kernel(const float* __restrict__ pf, const float* __restrict__ pm,
                            const float* __restrict__ vF, const float* __restrict__ vM,
                            float* __restrict__ diff) {
    int idx = blockIdx.x * blockDim.x + threadIdx.x;
    if (idx >= BATCH * PLANE_S) return;
    int b = idx >> 16;
    int r = idx & (PLANE_S - 1);
    int y = r >> 8, x = r & 255;
    const float* f = pf + (size_t)b * PLANE_S;
    const float* m = pm + (size_t)b * PLANE_S;
    float cF = f[r], cM = m[r];
    float dF2 = 2.f * vF[idx] + 1e-6f;
    float dM2 = 2.f * vM[idx] + 1e-6f;
    float eF[8], eM[8];
    float sF = 0.f, sM = 0.f;
    int ch = 0;
    #pragma unroll
    for (int i = -1; i <= 1; i++) {
        #pragma unroll
        for (int j = -1; j <= 1; j++) {
            if (i == 0 && j == 0) continue;
            int yy = clampi(y + j * 2, 0, HS - 1);
            int xx = clampi(x + i * 2, 0, WS - 1);
            int o = yy * WS + xx;
            float aF = cF - f[o];
            float aM = cM - m[o];
            float qF = fminf(aF * aF / dF2, 50.f);
            float qM = fminf(aM * aM / dM2, 50.f);
            float vFe = expf(-qF), vMe = expf(-qM);
            eF[ch] = vFe; eM[ch] = vMe;
            sF += vFe; sM += vMe;
            ch++;
        }
    }
    float wF = 1.f / (sF + 1e-8f);
    float wM = 1.f / (sM + 1e-8f);
    float* dbase = diff + (size_t)b * 8 * PLANE_S + r;
    #pragma unroll
    for (int c = 0; c < 8; c++) dbase[(size_t)c * PLANE_S] = eF[c] * wF - eM[c] * wM;
}

// Tiled bilinear align-corners upsample 256->512 + sum(|.|) reduction.
// Each block: one 128x128 OUTPUT tile of one plane; stages <=66x66 source patch in LDS.
#define TILE_OUT 128
#define LDS_ROWS 66
#define LDS_LOAD 66
#define LDS_STRIDE 68   // pad to avoid row-aligned banking

__global__ void mindsum_tiled_kernel(const float* __restrict__ diff, double* __restrict__ acc) {
    __shared__ float tile[LDS_ROWS * LDS_STRIDE];
    __shared__ double red[256];
    const float FS = (float)(255.0 / 511.0);
    int plane = blockIdx.y;                    // 0..63 (b*8+ch)
    int Yb = (blockIdx.x >> 2) * TILE_OUT;
    int Xb = (blockIdx.x & 3) * TILE_OUT;
    int ybase = (int)((float)Yb * FS);
    int xbase = (int)((float)Xb * FS);
    const float* pl = diff + (size_t)plane * PLANE_S;
    for (int i = threadIdx.x; i < LDS_ROWS * LDS_LOAD; i += 256) {
        int r = i / LDS_LOAD, c = i - r * LDS_LOAD;
        int gy = ybase + r; if (gy > HS - 1) gy = HS - 1;
        int gx = xbase + c; if (gx > WS - 1) gx = WS - 1;
        tile[r * LDS_STRIDE + c] = pl[gy * WS + gx];
    }
    __syncthreads();
    float local = 0.f;
    for (int k = threadIdx.x; k < TILE_OUT * TILE_OUT; k += 256) {
        int dy = k >> 7, dx = k & 127;
        float py = (float)(Yb + dy) * FS;
        int y0 = (int)py; if (y0 > HS - 2) y0 = HS - 2;
        float fy = py - (float)y0;
        float px = (float)(Xb + dx) * FS;
        int x0 = (int)px; if (x0 > WS - 2) x0 = WS - 2;
        float fx = px - (float)x0;
        const float* t0 = &tile[(y0 - ybase) * LDS_STRIDE + (x0 - xbase)];
        float a  = t0[0] * (1.f - fy) + t0[LDS_STRIDE] * fy;
        float c2 = t0[1] * (1.f - fy) + t0[LDS_STRIDE + 1] * fy;
        local += fabsf(a * (1.f - fx) + c2 * fx);
    }
    int t = threadIdx.x;
    red[t] = (double)local;
    __syncthreads();
    for (int s = 128; s > 0; s >>= 1) { if (t < s) red[t] += red[t + s]; __syncthreads(); }
    if (t == 0) atomicAdd(acc, red[0]);
}

// per-batch NMI from joint histogram
__global__ void nmi_kernel(const unsigned* __restrict__ hist, float* __restrict__ nmi_out) {
    int b = blockIdx.x;
    int t = threadIdx.x;  // 256
    __shared__ float p[256];
    __shared__ float xh[16], yh[16];
    __shared__ float red[256];
    float pv = (float)hist[b * 256 + t] / 65536.0f;  // sum+1e-10 == 65536 in fp32
    p[t] = pv;
    __syncthreads();
    if (t < 16) {
        float s = 0.f;
        for (int j = 0; j < 16; j++) s += p[t * 16 + j];
        xh[t] = s;
    } else if (t < 32) {
        int j = t - 16;
        float s = 0.f;
        for (int i = 0; i < 16; i++) s += p[i * 16 + j];
        yh[j] = s;
    }
    __syncthreads();
    const float eps = 1e-5f;
    int i = t >> 4, j = t & 15;
    float h = pv + eps;
    float mi_term = h * (logf(h) - logf((xh[i] + eps) * (yh[j] + eps)));
    red[t] = mi_term;
    __syncthreads();
    for (int s = 128; s > 0; s >>= 1) { if (t < s) red[t] += red[t + s]; __syncthreads(); }
    float mi = red[0];
    __syncthreads();
    float e_term = 0.f;
    if (t < 16) { float xe = xh[t] + eps; e_term = -xe * logf(xe); }
    else if (t < 32) { float ye = yh[t - 16] + eps; e_term = -ye * logf(ye); }
    red[t] = e_term;
    __syncthreads();
    for (int s = 128; s > 0; s >>= 1) { if (t < s) red[t] += red[t + s]; __syncthreads(); }
    if (t == 0) {
        float se = red[0];  // hx + hy
        float nmi = (se < 1e-10f) ? 0.f : 2.f * mi / se;
        nmi_out[b] = fminf(fmaxf(nmi, -1.f), 1.f);
    }
}

// Sobel grad + Laplacian magnitudes on pooled flow, clipped sums
__global__ void reg_kernel(const float* __restrict__ pflow, double* __restrict__ acc_grad,
                           double* __restrict__ acc_lap) {
    __shared__ double red[256];
    int idx = blockIdx.x * blockDim.x + threadIdx.x;
    double g = 0.0, l = 0.0;
    if (idx < BATCH * PLANE_S) {
        int b = idx >> 16;
        int r = idx & (PLANE_S - 1);
        int y = r >> 8, x = r & 255;
        const float* u = pflow + (size_t)b * 2 * PLANE_S;
        const float* v = u + PLANE_S;
        float a[3][3], c[3][3];
        #pragma unroll
        for (int dy = 0; dy < 3; dy++) {
            int yy = clampi(y + dy - 1, 0, HS - 1);
            #pragma unroll
            for (int dx = 0; dx < 3; dx++) {
                int xx = clampi(x + dx - 1, 0, WS - 1);
                a[dy][dx] = u[yy * WS + xx];
                c[dy][dx] = v[yy * WS + xx];
            }
        }
        float gxu = (a[0][2] - a[0][0]) + 2.f * (a[1][2] - a[1][0]) + (a[2][2] - a[2][0]);
        float gyu = (a[2][0] - a[0][0]) + 2.f * (a[2][1] - a[0][1]) + (a[2][2] - a[0][2]);
        float gxv = (c[0][2] - c[0][0]) + 2.f * (c[1][2] - c[1][0]) + (c[2][2] - c[2][0]);
        float gyv = (c[2][0] - c[0][0]) + 2.f * (c[2][1] - c[0][1]) + (c[2][2] - c[0][2]);
        float lpu = a[0][1] + a[1][0] - 4.f * a[1][1] + a[1][2] + a[2][1];
        float lpv = c[0][1] + c[1][0] - 4.f * c[1][1] + c[1][2] + c[2][1];
        float grad = gxu * gxu + gyu * gyu + gxv * gxv + gyv * gyv;
        float lap = lpu * lpu + lpv * lpv;
        g = (double)fminf(grad, 100.f);
        l = (double)fminf(lap, 100.f);
    }
    int t = threadIdx.x;
    red[t] = g;
    __syncthreads();
    for (int s = 128; s > 0; s >>= 1) { if (t < s) red[t] += red[t + s]; __syncthreads(); }
    if (t == 0) atomicAdd(acc_grad, red[0]);
    __syncthreads();
    red[t] = l;
    __syncthreads();
    for (int s = 128; s > 0; s >>= 1) { if (t < s) red[t] += red[t + s]; __syncthreads(); }
    if (t == 0) atomicAdd(acc_lap, red[0]);
}

__global__ void final_kernel(const float* __restrict__ nmi, const double* __restrict__ acc,
                             float* __restrict__ out) {
    float s = 0.f;
    for (int b = 0; b < BATCH; b++) s += nmi[b];
    s /= (float)BATCH;
    s = fminf(fmaxf(s, -1.f), 1.f);
    double mi_loss = -(double)s;
    double mind_mean = acc[0] / (64.0 * (double)PLANE_F);
    double reg = acc[1] / (double)(BATCH * PLANE_S) + acc[2] / (double)(BATCH * PLANE_S);
    out[0] = (float)(mi_loss + 5.0 * mind_mean + 0.1 * reg);
}

extern "C" void kernel_launch(void* const* d_in, const int* in_sizes, int n_in,
                              void* d_out, int out_size, void* d_ws, size_t ws_size,
                              hipStream_t stream) {
    const float* fixed = (const float*)d_in[0];
    const float* moved = (const float*)d_in[1];
    const float* flow  = (const float*)d_in[2];
    float* out = (float*)d_out;
    char* ws = (char*)d_ws;

    float*    pf    = (float*)(ws + OFF_PF);
    float*    pm    = (float*)(ws + OFF_PM);
    float*    pflow = (float*)(ws + OFF_PFLOW);
    float*    vF    = (float*)(ws + OFF_VF);
    float*    vM    = (float*)(ws + OFF_VM);
    float*    diffb = (float*)(ws + OFF_DIFF);
    float*    tFM   = (float*)(ws + OFF_TF);
    unsigned* hist  = (unsigned*)(ws + OFF_HIST);
    float*    nmi   = (float*)(ws + OFF_NMI);
    double*   acc   = (double*)(ws + OFF_ACC);

    init_kernel<<<1, 256, 0, stream>>>(hist, nmi, acc);

    // fused pool(fixed)+pool(moved)+histogram; flow pooled separately (16 planes)
    pool_fm_hist_kernel<<<dim3(PLANE_S / 256, BATCH), 256, 0, stream>>>(fixed, moved, pf, pm, hist);
    pool_kernel<<<(2 * BATCH * PLANE_S) / 256, 256, 0, stream>>>(flow, pflow, 2 * BATCH);

    // MIND variance (2 passes, F+M in one dispatch; pf/pm and vF/vM contiguous)
    patchvar1_kernel<<<(2 * BATCH * PLANE_S) / 256, 256, 0, stream>>>(pf, tFM, 2 * BATCH);
    patchvar2_kernel<<<(2 * BATCH * PLANE_S) / 256, 256, 0, stream>>>(tFM, vF, 2 * BATCH);

    mind_kernel<<<(BATCH * PLANE_S) / 256, 256, 0, stream>>>(pf, pm, vF, vM, diffb);
    mindsum_tiled_kernel<<<dim3(16, 64), 256, 0, stream>>>(diffb, acc);

    nmi_kernel<<<BATCH, 256, 0, stream>>>(hist, nmi);
    reg_kernel<<<(BATCH * PLANE_S) / 256, 256, 0, stream>>>(pflow, &acc[1], &acc[2]);

    final_kernel<<<1, 1, 0, stream>>>(nmi, acc, out);
}

// Round 3
// 138.726 us; speedup vs baseline: 1.9898x; 1.3624x over previous
//
#include <hip/hip_runtime.h>
#include <cmath>

// Problem constants
#define BATCH 8
#define HF 512
#define WF 512
#define HS 256
#define WS 256
#define PLANE_S (HS * WS)   // 65536
#define PLANE_F (HF * WF)   // 262144
#define MB (1048576)

#define NREG_BLOCKS 512
#define NMIND_BLOCKS 1024   // dim3(16,64)

// Workspace layout (bytes)
#define OFF_PF    (0)                 // pooled fixed:  8 * 65536 f  (2 MB)
#define OFF_PM    (2 * MB)            // pooled moved:  2 MB (contiguous after PF)
#define OFF_PFLOW (4 * MB)            // pooled flow:   16 planes (4 MB)
#define OFF_VF    (8 * MB)            // variance F:    2 MB
#define OFF_VM    (10 * MB)           // variance M:    2 MB (contiguous after VF)
#define OFF_DIFF  (12 * MB)           // mind diff:     8*8*65536 f (16 MB); tF/tM overlap here
#define OFF_TF    (OFF_DIFF)          // temp (img-mean)^2 F+M (4 MB, dead before diff written)
#define OFF_HIST  (28 * MB)           // 8 * 256 u32 = 8192 B
#define OFF_NMI   (28 * MB + 8192)    // 8 f32 = 32 B
#define OFF_PMIND (28 * MB + 8192 + 32)            // 1024 doubles = 8192 B
#define OFF_PGRAD (OFF_PMIND + NMIND_BLOCKS * 8)   // 512 doubles
#define OFF_PLAP  (OFF_PGRAD + NREG_BLOCKS * 8)    // 512 doubles

__device__ __forceinline__ int clampi(int v, int lo, int hi) {
    return v < lo ? lo : (v > hi ? hi : v);
}

__global__ void init_kernel(unsigned* hist) {
    int t = threadIdx.x;
    for (int i = t; i < BATCH * 256; i += 256) hist[i] = 0u;
}

__device__ __forceinline__ int bin_of(float x) {
    float v = (x + 1.0f) * 0.5f;
    v = fminf(fmaxf(v, 0.001f), 0.999f);
    float t = v * 16.0f;            // exact (power-of-2 scale)
    float ft = floorf(t);
    int c = (int)ft + ((t > ft) ? 1 : 0);   // searchsorted-left count of grid < v
    int b = c - 1;
    return b < 0 ? 0 : (b > 15 ? 15 : b);
}

// Fused: avg_pool2 of fixed & moved + joint 16x16 histogram of the ::2,::2 samples
__global__ void pool_fm_hist_kernel(const float* __restrict__ fixed, const float* __restrict__ moved,
                                    float* __restrict__ pf, float* __restrict__ pm,
                                    unsigned* __restrict__ hist) {
    int b = blockIdx.y;
    __shared__ unsigned lh[256];
    lh[threadIdx.x] = 0u;
    __syncthreads();
    int idx = blockIdx.x * 256 + threadIdx.x;   // 0..65535 within plane
    int y = idx >> 8, x = idx & 255;
    size_t so = (size_t)b * PLANE_F + (size_t)(y * 2) * WF + (size_t)(x * 2);
    const float* fb = fixed + so;
    const float* mb = moved + so;
    float f00 = fb[0], f01 = fb[1], f10 = fb[WF], f11 = fb[WF + 1];
    float m00 = mb[0], m01 = mb[1], m10 = mb[WF], m11 = mb[WF + 1];
    pf[(size_t)b * PLANE_S + idx] = (f00 + f01 + f10 + f11) * 0.25f;
    pm[(size_t)b * PLANE_S + idx] = (m00 + m01 + m10 + m11) * 0.25f;
    int xb = bin_of(f00), yb = bin_of(m00);
    atomicAdd(&lh[xb * 16 + yb], 1u);
    __syncthreads();
    unsigned v = lh[threadIdx.x];
    if (v) atomicAdd(&hist[b * 256 + threadIdx.x], v);
}

// plain avg_pool2 for flow (16 planes)
__global__ void pool_kernel(const float* __restrict__ src, float* __restrict__ dst, int nplanes) {
    int idx = blockIdx.x * blockDim.x + threadIdx.x;
    if (idx >= nplanes * PLANE_S) return;
    int p = idx >> 16;
    int r = idx & (PLANE_S - 1);
    int y = r >> 8, x = r & 255;
    const float* s = src + (size_t)p * PLANE_F + (size_t)(y * 2) * WF + (x * 2);
    dst[idx] = (s[0] + s[1] + s[WF] + s[WF + 1]) * 0.25f;
}

// t = (img[y,x] - boxmean centered at (y-1,x-1))^2   [reference pad/slice quirk]
__global__ void patchvar1_kernel(const float* __restrict__ img, float* __restrict__ t, int nplanes) {
    int idx = blockIdx.x * blockDim.x + threadIdx.x;
    if (idx >= nplanes * PLANE_S) return;
    int p = idx >> 16;
    int r = idx & (PLANE_S - 1);
    int y = r >> 8, x = r & 255;
    const float* pp = img + (size_t)p * PLANE_S;
    float s = 0.f;
    #pragma unroll
    for (int dy = -2; dy <= 0; dy++) {
        int yy = clampi(y + dy, 0, HS - 1);
        #pragma unroll
        for (int dx = -2; dx <= 0; dx++) {
            int xx = clampi(x + dx, 0, WS - 1);
            s += pp[yy * WS + xx];
        }
    }
    float mean = s / 9.0f;
    float d = pp[r] - mean;
    t[idx] = d * d;
}

// var = max(box3x3(t)/9, 1e-4)
__global__ void patchvar2_kernel(const float* __restrict__ t, float* __restrict__ var, int nplanes) {
    int idx = blockIdx.x * blockDim.x + threadIdx.x;
    if (idx >= nplanes * PLANE_S) return;
    int p = idx >> 16;
    int r = idx & (PLANE_S - 1);
    int y = r >> 8, x = r & 255;
    const float* pp = t + (size_t)p * PLANE_S;
    float s = 0.f;
    #pragma unroll
    for (int dy = -1; dy <= 1; dy++) {
        int yy = clampi(y + dy, 0, HS - 1);
        #pragma unroll
        for (int dx = -1; dx <= 1; dx++) {
            int xx = clampi(x + dx, 0, WS - 1);
            s += pp[yy * WS + xx];
        }
    }
    var[idx] = fmaxf(s / 9.0f, 1e-4f);
}

// MIND descriptors for both images, store diff = mF - mM, channel-major planes
__global__ void mind_kernel(const float* __restrict__ pf, const float* __restrict__ pm,
                            const float* __restrict__ vF, const float* __restrict__ vM,
                            float* __restrict__ diff) {
    int idx = blockIdx.x * blockDim.x + threadIdx.x;
    if (idx >= BATCH * PLANE_S) return;
    int b = idx >> 16;
    int r = idx & (PLANE_S - 1);
    int y = r >> 8, x = r & 255;
    const float* f = pf + (size_t)b * PLANE_S;
    const float* m = pm + (size_t)b * PLANE_S;
    float cF = f[r], cM = m[r];
    float dF2 = 2.f * vF[idx] + 1e-6f;
    float dM2 = 2.f * vM[idx] + 1e-6f;
    float eF[8], eM[8];
    float sF = 0.f, sM = 0.f;
    int ch = 0;
    #pragma unroll
    for (int i = -1; i <= 1; i++) {
        #pragma unroll
        for (int j = -1; j <= 1; j++) {
            if (i == 0 && j == 0) continue;
            int yy = clampi(y + j * 2, 0, HS - 1);
            int xx = clampi(x + i * 2, 0, WS - 1);
            int o = yy * WS + xx;
            float aF = cF - f[o];
            float aM = cM - m[o];
            float qF = fminf(aF * aF / dF2, 50.f);
            float qM = fminf(aM * aM / dM2, 50.f);
            float vFe = expf(-qF), vMe = expf(-qM);
            eF[ch] = vFe; eM[ch] = vMe;
            sF += vFe; sM += vMe;
            ch++;
        }
    }
    float wF = 1.f / (sF + 1e-8f);
    float wM = 1.f / (sM + 1e-8f);
    float* dbase = diff + (size_t)b * 8 * PLANE_S + r;
    #pragma unroll
    for (int c = 0; c < 8; c++) dbase[(size_t)c * PLANE_S] = eF[c] * wF - eM[c] * wM;
}

// Tiled bilinear align-corners upsample 256->512 + sum(|.|), per-block partial (no atomics)
#define TILE_OUT 128
#define LDS_ROWS 66
#define LDS_LOAD 66
#define LDS_STRIDE 68

__global__ void mindsum_tiled_kernel(const float* __restrict__ diff, double* __restrict__ part) {
    __shared__ float tile[LDS_ROWS * LDS_STRIDE];
    __shared__ double red[256];
    const float FS = (float)(255.0 / 511.0);
    int plane = blockIdx.y;                    // 0..63 (b*8+ch)
    int Yb = (blockIdx.x >> 2) * TILE_OUT;
    int Xb = (blockIdx.x & 3) * TILE_OUT;
    int ybase = (int)((float)Yb * FS);
    int xbase = (int)((float)Xb * FS);
    const float* pl = diff + (size_t)plane * PLANE_S;
    for (int i = threadIdx.x; i < LDS_ROWS * LDS_LOAD; i += 256) {
        int r = i / LDS_LOAD, c = i - r * LDS_LOAD;
        int gy = ybase + r; if (gy > HS - 1) gy = HS - 1;
        int gx = xbase + c; if (gx > WS - 1) gx = WS - 1;
        tile[r * LDS_STRIDE + c] = pl[gy * WS + gx];
    }
    __syncthreads();
    float local = 0.f;
    for (int k = threadIdx.x; k < TILE_OUT * TILE_OUT; k += 256) {
        int dy = k >> 7, dx = k & 127;
        float py = (float)(Yb + dy) * FS;
        int y0 = (int)py; if (y0 > HS - 2) y0 = HS - 2;
        float fy = py - (float)y0;
        float px = (float)(Xb + dx) * FS;
        int x0 = (int)px; if (x0 > WS - 2) x0 = WS - 2;
        float fx = px - (float)x0;
        const float* t0 = &tile[(y0 - ybase) * LDS_STRIDE + (x0 - xbase)];
        float a  = t0[0] * (1.f - fy) + t0[LDS_STRIDE] * fy;
        float c2 = t0[1] * (1.f - fy) + t0[LDS_STRIDE + 1] * fy;
        local += fabsf(a * (1.f - fx) + c2 * fx);
    }
    int t = threadIdx.x;
    red[t] = (double)local;
    __syncthreads();
    for (int s = 128; s > 0; s >>= 1) { if (t < s) red[t] += red[t + s]; __syncthreads(); }
    if (t == 0) part[blockIdx.y * 16 + blockIdx.x] = red[0];
}

// per-batch NMI from joint histogram
__global__ void nmi_kernel(const unsigned* __restrict__ hist, float* __restrict__ nmi_out) {
    int b = blockIdx.x;
    int t = threadIdx.x;  // 256
    __shared__ float p[256];
    __shared__ float xh[16], yh[16];
    __shared__ float red[256];
    float pv = (float)hist[b * 256 + t] / 65536.0f;  // sum+1e-10 == 65536 in fp32
    p[t] = pv;
    __syncthreads();
    if (t < 16) {
        float s = 0.f;
        for (int j = 0; j < 16; j++) s += p[t * 16 + j];
        xh[t] = s;
    } else if (t < 32) {
        int j = t - 16;
        float s = 0.f;
        for (int i = 0; i < 16; i++) s += p[i * 16 + j];
        yh[j] = s;
    }
    __syncthreads();
    const float eps = 1e-5f;
    int i = t >> 4, j = t & 15;
    float h = pv + eps;
    float mi_term = h * (logf(h) - logf((xh[i] + eps) * (yh[j] + eps)));
    red[t] = mi_term;
    __syncthreads();
    for (int s = 128; s > 0; s >>= 1) { if (t < s) red[t] += red[t + s]; __syncthreads(); }
    float mi = red[0];
    __syncthreads();
    float e_term = 0.f;
    if (t < 16) { float xe = xh[t] + eps; e_term = -xe * logf(xe); }
    else if (t < 32) { float ye = yh[t - 16] + eps; e_term = -ye * logf(ye); }
    red[t] = e_term;
    __syncthreads();
    for (int s = 128; s > 0; s >>= 1) { if (t < s) red[t] += red[t + s]; __syncthreads(); }
    if (t == 0) {
        float se = red[0];  // hx + hy
        float nmi = (se < 1e-10f) ? 0.f : 2.f * mi / se;
        nmi_out[b] = fminf(fmaxf(nmi, -1.f), 1.f);
    }
}

// Sobel grad + Laplacian on pooled flow; grid-stride; per-block partials (no atomics)
__global__ void reg_kernel(const float* __restrict__ pflow, double* __restrict__ pgrad,
                           double* __restrict__ plap) {
    __shared__ double red[256];
    const int N = BATCH * PLANE_S;
    int stride = gridDim.x * blockDim.x;
    double g = 0.0, l = 0.0;
    for (int idx = blockIdx.x * blockDim.x + threadIdx.x; idx < N; idx += stride) {
        int b = idx >> 16;
        int r = idx & (PLANE_S - 1);
        int y = r >> 8, x = r & 255;
        const float* u = pflow + (size_t)b * 2 * PLANE_S;
        const float* v = u + PLANE_S;
        float a[3][3], c[3][3];
        #pragma unroll
        for (int dy = 0; dy < 3; dy++) {
            int yy = clampi(y + dy - 1, 0, HS - 1);
            #pragma unroll
            for (int dx = 0; dx < 3; dx++) {
                int xx = clampi(x + dx - 1, 0, WS - 1);
                a[dy][dx] = u[yy * WS + xx];
                c[dy][dx] = v[yy * WS + xx];
            }
        }
        float gxu = (a[0][2] - a[0][0]) + 2.f * (a[1][2] - a[1][0]) + (a[2][2] - a[2][0]);
        float gyu = (a[2][0] - a[0][0]) + 2.f * (a[2][1] - a[0][1]) + (a[2][2] - a[0][2]);
        float gxv = (c[0][2] - c[0][0]) + 2.f * (c[1][2] - c[1][0]) + (c[2][2] - c[2][0]);
        float gyv = (c[2][0] - c[0][0]) + 2.f * (c[2][1] - c[0][1]) + (c[2][2] - c[0][2]);
        float lpu = a[0][1] + a[1][0] - 4.f * a[1][1] + a[1][2] + a[2][1];
        float lpv = c[0][1] + c[1][0] - 4.f * c[1][1] + c[1][2] + c[2][1];
        float grad = gxu * gxu + gyu * gyu + gxv * gxv + gyv * gyv;
        float lap = lpu * lpu + lpv * lpv;
        g += (double)fminf(grad, 100.f);
        l += (double)fminf(lap, 100.f);
    }
    int t = threadIdx.x;
    red[t] = g;
    __syncthreads();
    for (int s = 128; s > 0; s >>= 1) { if (t < s) red[t] += red[t + s]; __syncthreads(); }
    if (t == 0) pgrad[blockIdx.x] = red[0];
    __syncthreads();
    red[t] = l;
    __syncthreads();
    for (int s = 128; s > 0; s >>= 1) { if (t < s) red[t] += red[t + s]; __syncthreads(); }
    if (t == 0) plap[blockIdx.x] = red[0];
}

// Reduce all partials + nmi -> final scalar
__global__ void final_kernel(const float* __restrict__ nmi, const double* __restrict__ pmind,
                             const double* __restrict__ pgrad, const double* __restrict__ plap,
                             float* __restrict__ out) {
    __shared__ double red[256];
    int t = threadIdx.x;
    double sm = 0.0;
    for (int i = t; i < NMIND_BLOCKS; i += 256) sm += pmind[i];
    double sg = 0.0, sl = 0.0;
    for (int i = t; i < NREG_BLOCKS; i += 256) { sg += pgrad[i]; sl += plap[i]; }
    red[t] = sm;
    __syncthreads();
    for (int s = 128; s > 0; s >>= 1) { if (t < s) red[t] += red[t + s]; __syncthreads(); }
    double mind_sum = red[0];
    __syncthreads();
    red[t] = sg;
    __syncthreads();
    for (int s = 128; s > 0; s >>= 1) { if (t < s) red[t] += red[t + s]; __syncthreads(); }
    double grad_sum = red[0];
    __syncthreads();
    red[t] = sl;
    __syncthreads();
    for (int s = 128; s > 0; s >>= 1) { if (t < s) red[t] += red[t + s]; __syncthreads(); }
    double lap_sum = red[0];
    if (t == 0) {
        float s = 0.f;
        for (int b = 0; b < BATCH; b++) s += nmi[b];
        s /= (float)BATCH;
        s = fminf(fmaxf(s, -1.f), 1.f);
        double mi_loss = -(double)s;
        double mind_mean = mind_sum / (64.0 * (double)PLANE_F);
        double reg = grad_sum / (double)(BATCH * PLANE_S) + lap_sum / (double)(BATCH * PLANE_S);
        out[0] = (float)(mi_loss + 5.0 * mind_mean + 0.1 * reg);
    }
}

extern "C" void kernel_launch(void* const* d_in, const int* in_sizes, int n_in,
                              void* d_out, int out_size, void* d_ws, size_t ws_size,
                              hipStream_t stream) {
    const float* fixed = (const float*)d_in[0];
    const float* moved = (const float*)d_in[1];
    const float* flow  = (const float*)d_in[2];
    float* out = (float*)d_out;
    char* ws = (char*)d_ws;

    float*    pf    = (float*)(ws + OFF_PF);
    float*    pm    = (float*)(ws + OFF_PM);
    float*    pflow = (float*)(ws + OFF_PFLOW);
    float*    vF    = (float*)(ws + OFF_VF);
    float*    diffb = (float*)(ws + OFF_DIFF);
    float*    tFM   = (float*)(ws + OFF_TF);
    unsigned* hist  = (unsigned*)(ws + OFF_HIST);
    float*    nmi   = (float*)(ws + OFF_NMI);
    double*   pmind = (double*)(ws + OFF_PMIND);
    double*   pgrad = (double*)(ws + OFF_PGRAD);
    double*   plap  = (double*)(ws + OFF_PLAP);
    float*    vM    = (float*)(ws + OFF_VM);

    init_kernel<<<1, 256, 0, stream>>>(hist);

    pool_fm_hist_kernel<<<dim3(PLANE_S / 256, BATCH), 256, 0, stream>>>(fixed, moved, pf, pm, hist);
    pool_kernel<<<(2 * BATCH * PLANE_S) / 256, 256, 0, stream>>>(flow, pflow, 2 * BATCH);

    patchvar1_kernel<<<(2 * BATCH * PLANE_S) / 256, 256, 0, stream>>>(pf, tFM, 2 * BATCH);
    patchvar2_kernel<<<(2 * BATCH * PLANE_S) / 256, 256, 0, stream>>>(tFM, vF, 2 * BATCH);

    mind_kernel<<<(BATCH * PLANE_S) / 256, 256, 0, stream>>>(pf, pm, vF, vM, diffb);
    mindsum_tiled_kernel<<<dim3(16, 64), 256, 0, stream>>>(diffb, pmind);

    nmi_kernel<<<BATCH, 256, 0, stream>>>(hist, nmi);
    reg_kernel<<<NREG_BLOCKS, 256, 0, stream>>>(pflow, pgrad, plap);

    final_kernel<<<1, 256, 0, stream>>>(nmi, pmind, pgrad, plap, out);
}

// Round 4
// 115.084 us; speedup vs baseline: 2.3986x; 1.2054x over previous
//
#include <hip/hip_runtime.h>
#include <cmath>

// Problem constants
#define BATCH 8
#define HF 512
#define WF 512
#define HS 256
#define WS 256
#define PLANE_S (HS * WS)   // 65536
#define PLANE_F (HF * WF)   // 262144

#define NMIND_BLOCKS 512    // 8x8 tiles x 8 batches
#define NREG_BLOCKS  128    // 4x4 tiles x 8 batches

// Workspace layout (bytes) — everything fully written before read, no init needed
#define OFF_HISTP 0                          // 8*64*256 u32 = 512 KB (per-block hist partials)
#define OFF_PMIND (512 * 1024)               // 512 doubles
#define OFF_PGRAD (OFF_PMIND + NMIND_BLOCKS * 8)
#define OFF_PLAP  (OFF_PGRAD + NREG_BLOCKS * 8)
#define OFF_NMI   (OFF_PLAP + NREG_BLOCKS * 8)   // 8 f32

// mega-kernel patch geometry (64x64 output tile)
#define IMG_R 39   // pooled img patch rows/cols (halo: var 5x5 + MIND dil-2 + bilinear +1)
#define IMG_S 41   // LDS stride (odd)
#define T_R 36     // (img - offset-boxmean)^2 patch
#define T_S 37
#define V_R 34     // variance / diff patch
#define V_S 35

__device__ __forceinline__ int clampi(int v, int lo, int hi) {
    return v < lo ? lo : (v > hi ? hi : v);
}

__device__ __forceinline__ int bin_of(float x) {
    float v = (x + 1.0f) * 0.5f;
    v = fminf(fmaxf(v, 0.001f), 0.999f);
    float t = v * 16.0f;            // exact (power-of-2 scale)
    float ft = floorf(t);
    int c = (int)ft + ((t > ft) ? 1 : 0);   // searchsorted-left count of grid < v
    int b = c - 1;
    return b < 0 ? 0 : (b > 15 ? 15 : b);
}

// ONE kernel: pool(F,M) -> patchmean -> variance -> MIND(F,M) -> diff -> bilinear
// upsample -> sum|.|  + joint histogram of the ::2,::2 raw samples (owned core only).
// Block = one 64x64 output tile of one batch. grid = (8 tx, 8 ty, 8 b).
__global__ __launch_bounds__(256, 2) void mega_mind_kernel(
    const float* __restrict__ fixed, const float* __restrict__ moved,
    unsigned* __restrict__ hist_part, double* __restrict__ pmind)
{
    const float FS = (float)(255.0 / 511.0);
    int tx = blockIdx.x, ty = blockIdx.y, b = blockIdx.z;
    int Xb = tx * 64, Yb = ty * 64;
    int dbx = (int)((float)Xb * FS);   // min x0 over the tile (fp32 multiply is monotone)
    int dby = (int)((float)Yb * FS);
    int ibx = dbx - 3, iby = dby - 3;  // pooled img patch base

    // 15098 floats = 60.4 KB; t aliases the (later) diff region
    __shared__ float S[15098];
    float* imgF = S;                        // 39*41 = 1599
    float* imgM = S + IMG_R * IMG_S;        // 1599
    float* varF = S + 2 * IMG_R * IMG_S;    // 34*35 = 1190
    float* varM = varF + V_R * V_S;         // 1190
    float* diff = varM + V_R * V_S;         // 34*35*8 = 9520, channel-interleaved
    float* tF   = diff;                     // 36*37 = 1332 (dead before diff written)
    float* tM   = diff + T_R * T_S;         // 1332
    __shared__ unsigned lh[256];
    __shared__ float red[256];

    int tid = threadIdx.x;
    lh[tid] = 0u;
    __syncthreads();

    // ---- stage pooled F/M patches (clamp-at-staging = edge-pad semantics) + histogram
    const float* fb = fixed + (size_t)b * PLANE_F;
    const float* mb = moved + (size_t)b * PLANE_F;
    int oy0 = ty * 32, ox0 = tx * 32;   // owned pooled box for the histogram (exact cover)
    for (int i = tid; i < IMG_R * IMG_R; i += 256) {
        int r = i / IMG_R, c = i - r * IMG_R;
        int gy = iby + r, gx = ibx + c;
        int cy = clampi(gy, 0, HS - 1), cx = clampi(gx, 0, WS - 1);
        const float* fp = fb + (size_t)(cy * 2) * WF + (size_t)(cx * 2);
        const float* mp = mb + (size_t)(cy * 2) * WF + (size_t)(cx * 2);
        float2 f0 = *(const float2*)fp;
        float2 f1 = *(const float2*)(fp + WF);
        float2 m0 = *(const float2*)mp;
        float2 m1 = *(const float2*)(mp + WF);
        imgF[r * IMG_S + c] = (f0.x + f0.y + f1.x + f1.y) * 0.25f;
        imgM[r * IMG_S + c] = (m0.x + m0.y + m1.x + m1.y) * 0.25f;
        // ::2,::2 histogram sample = top-left raw pixel of the pool window
        if ((unsigned)(gy - oy0) < 32u && (unsigned)(gx - ox0) < 32u) {
            atomicAdd(&lh[bin_of(f0.x) * 16 + bin_of(m0.x)], 1u);
        }
    }
    __syncthreads();
    // histogram partial out (plain store, no global atomics)
    hist_part[((size_t)(b * 64 + ty * 8 + tx)) * 256 + tid] = lh[tid];

    // ---- t = (img[q] - boxmean(img[q-2..q]))^2   [reference pad/slice quirk]
    for (int i = tid; i < T_R * T_R; i += 256) {
        int r = i / T_R, c = i - r * T_R;
        float sF = 0.f, sM = 0.f;
        #pragma unroll
        for (int dy = 0; dy < 3; dy++)
            #pragma unroll
            for (int dx = 0; dx < 3; dx++) {
                sF += imgF[(r + dy) * IMG_S + c + dx];
                sM += imgM[(r + dy) * IMG_S + c + dx];
            }
        float dF = imgF[(r + 2) * IMG_S + c + 2] - sF / 9.0f;
        float dM = imgM[(r + 2) * IMG_S + c + 2] - sM / 9.0f;
        tF[r * T_S + c] = dF * dF;
        tM[r * T_S + c] = dM * dM;
    }
    __syncthreads();

    // ---- var = max(box3x3(t)/9, 1e-4)
    for (int i = tid; i < V_R * V_R; i += 256) {
        int r = i / V_R, c = i - r * V_R;
        float sF = 0.f, sM = 0.f;
        #pragma unroll
        for (int dy = 0; dy < 3; dy++)
            #pragma unroll
            for (int dx = 0; dx < 3; dx++) {
                sF += tF[(r + dy) * T_S + c + dx];
                sM += tM[(r + dy) * T_S + c + dx];
            }
        varF[r * V_S + c] = fmaxf(sF / 9.0f, 1e-4f);
        varM[r * V_S + c] = fmaxf(sM / 9.0f, 1e-4f);
    }
    __syncthreads();

    // ---- MIND + diff (overwrites the dead t region), channel-interleaved for b128 reads
    for (int i = tid; i < V_R * V_R; i += 256) {
        int r = i / V_R, c = i - r * V_R;
        float cF = imgF[(r + 3) * IMG_S + c + 3];
        float cM = imgM[(r + 3) * IMG_S + c + 3];
        float dF2 = 2.f * varF[r * V_S + c] + 1e-6f;
        float dM2 = 2.f * varM[r * V_S + c] + 1e-6f;
        float eF[8], eM[8];
        float sF = 0.f, sM = 0.f;
        int ch = 0;
        #pragma unroll
        for (int ii = -1; ii <= 1; ii++) {
            #pragma unroll
            for (int jj = -1; jj <= 1; jj++) {
                if (ii == 0 && jj == 0) continue;
                float aF = cF - imgF[(r + 3 + 2 * jj) * IMG_S + (c + 3 + 2 * ii)];
                float aM = cM - imgM[(r + 3 + 2 * jj) * IMG_S + (c + 3 + 2 * ii)];
                float qF = fminf(aF * aF / dF2, 50.f);
                float qM = fminf(aM * aM / dM2, 50.f);
                float vF_ = expf(-qF), vM_ = expf(-qM);
                eF[ch] = vF_; eM[ch] = vM_;
                sF += vF_; sM += vM_;
                ch++;
            }
        }
        float wF = 1.f / (sF + 1e-8f);
        float wM = 1.f / (sM + 1e-8f);
        float* dp = diff + (size_t)(r * V_S + c) * 8;
        #pragma unroll
        for (int q = 0; q < 8; q++) dp[q] = eF[q] * wF - eM[q] * wM;
    }
    __syncthreads();

    // ---- bilinear align-corners upsample + sum|.| (exact reference association)
    float local = 0.f;
    for (int k = tid; k < 64 * 64; k += 256) {
        int dy = k >> 6, dx = k & 63;
        float py = (float)(Yb + dy) * FS;
        int y0 = (int)py; if (y0 > HS - 2) y0 = HS - 2;
        float fy = py - (float)y0;
        float px = (float)(Xb + dx) * FS;
        int x0 = (int)px; if (x0 > WS - 2) x0 = WS - 2;
        float fx = px - (float)x0;
        const float* p00 = diff + (size_t)((y0 - dby) * V_S + (x0 - dbx)) * 8;
        const float* p10 = p00 + V_S * 8;
        #pragma unroll
        for (int q = 0; q < 8; q++) {
            float a  = p00[q]     * (1.f - fy) + p10[q]     * fy;
            float c2 = p00[q + 8] * (1.f - fy) + p10[q + 8] * fy;
            local += fabsf(a * (1.f - fx) + c2 * fx);
        }
    }
    red[tid] = local;
    __syncthreads();
    for (int s = 128; s > 0; s >>= 1) { if (tid < s) red[tid] += red[tid + s]; __syncthreads(); }
    if (tid == 0) pmind[b * 64 + ty * 8 + tx] = (double)red[0];
}

// Fused: pool(flow) -> Sobel + Laplacian -> clipped partial sums.
// Block = one 64x64 pooled tile of one batch. grid = (16 tiles, 8 b).
#define RP 66
#define RS 67
__global__ __launch_bounds__(256, 2) void reg_fused_kernel(
    const float* __restrict__ flow, double* __restrict__ pgrad, double* __restrict__ plap)
{
    int tt = blockIdx.x;          // 0..15
    int b = blockIdx.y;
    int tyr = tt >> 2, txr = tt & 3;
    int y0p = tyr * 64, x0p = txr * 64;
    __shared__ float U[RP * RS], V[RP * RS];
    __shared__ float red[256];
    const float* ur = flow + (size_t)(b * 2) * PLANE_F;
    const float* vr = ur + PLANE_F;
    int tid = threadIdx.x;
    for (int i = tid; i < RP * RP; i += 256) {
        int r = i / RP, c = i - r * RP;
        int gy = clampi(y0p - 1 + r, 0, HS - 1);
        int gx = clampi(x0p - 1 + c, 0, WS - 1);
        const float* uu = ur + (size_t)(gy * 2) * WF + (size_t)(gx * 2);
        const float* vv = vr + (size_t)(gy * 2) * WF + (size_t)(gx * 2);
        float2 u0 = *(const float2*)uu, u1 = *(const float2*)(uu + WF);
        float2 v0 = *(const float2*)vv, v1 = *(const float2*)(vv + WF);
        U[r * RS + c] = (u0.x + u0.y + u1.x + u1.y) * 0.25f;
        V[r * RS + c] = (v0.x + v0.y + v1.x + v1.y) * 0.25f;
    }
    __syncthreads();
    float g = 0.f, l = 0.f;
    for (int k = tid; k < 64 * 64; k += 256) {
        int y = k >> 6, x = k & 63;
        const float* u0 = &U[y * RS + x];
        const float* v0 = &V[y * RS + x];
        float a00 = u0[0],      a01 = u0[1],          a02 = u0[2];
        float a10 = u0[RS],     a11 = u0[RS + 1],     a12 = u0[RS + 2];
        float a20 = u0[2 * RS], a21 = u0[2 * RS + 1], a22 = u0[2 * RS + 2];
        float c00 = v0[0],      c01 = v0[1],          c02 = v0[2];
        float c10 = v0[RS],     c11 = v0[RS + 1],     c12 = v0[RS + 2];
        float c20 = v0[2 * RS], c21 = v0[2 * RS + 1], c22 = v0[2 * RS + 2];
        float gxu = (a02 - a00) + 2.f * (a12 - a10) + (a22 - a20);
        float gyu = (a20 - a00) + 2.f * (a21 - a01) + (a22 - a02);
        float gxv = (c02 - c00) + 2.f * (c12 - c10) + (c22 - c20);
        float gyv = (c20 - c00) + 2.f * (c21 - c01) + (c22 - c02);
        float lpu = a01 + a10 - 4.f * a11 + a12 + a21;
        float lpv = c01 + c10 - 4.f * c11 + c12 + c21;
        float grad = gxu * gxu + gyu * gyu + gxv * gxv + gyv * gyv;
        float lap = lpu * lpu + lpv * lpv;
        g += fminf(grad, 100.f);
        l += fminf(lap, 100.f);
    }
    red[tid] = g;
    __syncthreads();
    for (int s = 128; s > 0; s >>= 1) { if (tid < s) red[tid] += red[tid + s]; __syncthreads(); }
    if (tid == 0) pgrad[b * 16 + tt] = (double)red[0];
    __syncthreads();
    red[tid] = l;
    __syncthreads();
    for (int s = 128; s > 0; s >>= 1) { if (tid < s) red[tid] += red[tid + s]; __syncthreads(); }
    if (tid == 0) plap[b * 16 + tt] = (double)red[0];
}

// per-batch NMI from the 64 per-block histogram partials
__global__ void nmi_kernel(const unsigned* __restrict__ hist_part, float* __restrict__ nmi_out) {
    int b = blockIdx.x;
    int t = threadIdx.x;  // 256
    __shared__ float p[256];
    __shared__ float xh[16], yh[16];
    __shared__ float red[256];
    unsigned hv = 0;
    const unsigned* hp = hist_part + (size_t)b * 64 * 256 + t;
    for (int i = 0; i < 64; i++) hv += hp[i * 256];
    float pv = (float)hv / 65536.0f;  // sum+1e-10 == 65536 in fp32
    p[t] = pv;
    __syncthreads();
    if (t < 16) {
        float s = 0.f;
        for (int j = 0; j < 16; j++) s += p[t * 16 + j];
        xh[t] = s;
    } else if (t < 32) {
        int j = t - 16;
        float s = 0.f;
        for (int i = 0; i < 16; i++) s += p[i * 16 + j];
        yh[j] = s;
    }
    __syncthreads();
    const float eps = 1e-5f;
    int i = t >> 4, j = t & 15;
    float h = pv + eps;
    float mi_term = h * (logf(h) - logf((xh[i] + eps) * (yh[j] + eps)));
    red[t] = mi_term;
    __syncthreads();
    for (int s = 128; s > 0; s >>= 1) { if (t < s) red[t] += red[t + s]; __syncthreads(); }
    float mi = red[0];
    __syncthreads();
    float e_term = 0.f;
    if (t < 16) { float xe = xh[t] + eps; e_term = -xe * logf(xe); }
    else if (t < 32) { float ye = yh[t - 16] + eps; e_term = -ye * logf(ye); }
    red[t] = e_term;
    __syncthreads();
    for (int s = 128; s > 0; s >>= 1) { if (t < s) red[t] += red[t + s]; __syncthreads(); }
    if (t == 0) {
        float se = red[0];  // hx + hy
        float nmi = (se < 1e-10f) ? 0.f : 2.f * mi / se;
        nmi_out[b] = fminf(fmaxf(nmi, -1.f), 1.f);
    }
}

// Reduce all partials + nmi -> final scalar
__global__ void final_kernel(const float* __restrict__ nmi, const double* __restrict__ pmind,
                             const double* __restrict__ pgrad, const double* __restrict__ plap,
                             float* __restrict__ out) {
    __shared__ double red[256];
    int t = threadIdx.x;
    double sm = 0.0;
    for (int i = t; i < NMIND_BLOCKS; i += 256) sm += pmind[i];
    double sg = 0.0, sl = 0.0;
    for (int i = t; i < NREG_BLOCKS; i += 256) { sg += pgrad[i]; sl += plap[i]; }
    red[t] = sm;
    __syncthreads();
    for (int s = 128; s > 0; s >>= 1) { if (t < s) red[t] += red[t + s]; __syncthreads(); }
    double mind_sum = red[0];
    __syncthreads();
    red[t] = sg;
    __syncthreads();
    for (int s = 128; s > 0; s >>= 1) { if (t < s) red[t] += red[t + s]; __syncthreads(); }
    double grad_sum = red[0];
    __syncthreads();
    red[t] = sl;
    __syncthreads();
    for (int s = 128; s > 0; s >>= 1) { if (t < s) red[t] += red[t + s]; __syncthreads(); }
    double lap_sum = red[0];
    if (t == 0) {
        float s = 0.f;
        for (int b = 0; b < BATCH; b++) s += nmi[b];
        s /= (float)BATCH;
        s = fminf(fmaxf(s, -1.f), 1.f);
        double mi_loss = -(double)s;
        double mind_mean = mind_sum / (64.0 * (double)PLANE_F);
        double reg = grad_sum / (double)(BATCH * PLANE_S) + lap_sum / (double)(BATCH * PLANE_S);
        out[0] = (float)(mi_loss + 5.0 * mind_mean + 0.1 * reg);
    }
}

extern "C" void kernel_launch(void* const* d_in, const int* in_sizes, int n_in,
                              void* d_out, int out_size, void* d_ws, size_t ws_size,
                              hipStream_t stream) {
    const float* fixed = (const float*)d_in[0];
    const float* moved = (const float*)d_in[1];
    const float* flow  = (const float*)d_in[2];
    float* out = (float*)d_out;
    char* ws = (char*)d_ws;

    unsigned* hist_part = (unsigned*)(ws + OFF_HISTP);
    double*   pmind     = (double*)(ws + OFF_PMIND);
    double*   pgrad     = (double*)(ws + OFF_PGRAD);
    double*   plap      = (double*)(ws + OFF_PLAP);
    float*    nmi       = (float*)(ws + OFF_NMI);

    mega_mind_kernel<<<dim3(8, 8, 8), 256, 0, stream>>>(fixed, moved, hist_part, pmind);
    reg_fused_kernel<<<dim3(16, 8), 256, 0, stream>>>(flow, pgrad, plap);
    nmi_kernel<<<BATCH, 256, 0, stream>>>(hist_part, nmi);
    final_kernel<<<1, 256, 0, stream>>>(nmi, pmind, pgrad, plap, out);
}